// Round 3
// baseline (802.339 us; speedup 1.0000x reference)
//
#include <hip/hip_runtime.h>

// B=8, N=2048, D=F=768. out = softmax((X Wq)(X Wk)^T) (X Wv), fp32 I/O.
// Identity: S = X M X^T with M = Wq Wk^T -> keys = X (fp32 input), no K storage.
// ws: G = fp16(X M) [16384][768] | Vt = fp16(X Wv)^T [8][768][2048]  (50,331,648 B total)
// d_out scratch (consumed before attn writes out): MT fp32, WvT fp16.

typedef __attribute__((ext_vector_type(8))) _Float16 half8;
typedef __attribute__((ext_vector_type(4))) _Float16 half4v;
typedef __attribute__((ext_vector_type(4))) float floatx4;

__device__ __forceinline__ _Float16 f2h(float f) { return (_Float16)f; }
#define MFMA16 __builtin_amdgcn_mfma_f32_16x16x32_f16

// ---------------- MT[e][d] = (Wq Wk^T)^T, fp32 ----------------
__global__ __launch_bounds__(256) void mm_small_kernel(const float* __restrict__ Wq,
    const float* __restrict__ Wk, float* __restrict__ MT) {
  __shared__ _Float16 As[128][72];
  __shared__ _Float16 Bs[128][72];
  int bn = blockIdx.x, bm = blockIdx.y;
  int tid = threadIdx.x, lane = tid & 63, wave = tid >> 6;
  int wm = wave >> 1, wn = wave & 1;
  int l15 = lane & 15, quad = lane >> 4;
  floatx4 acc[16];
  for (int i = 0; i < 16; i++) acc[i] = (floatx4){0.f, 0.f, 0.f, 0.f};
  for (int k0 = 0; k0 < 768; k0 += 64) {
    __syncthreads();
    for (int i = 0; i < 8; i++) {
      int f = i * 256 + tid;
      int row = f >> 4, c4 = (f & 15) << 2;
      float4 va = *(const float4*)(Wq + (size_t)(bm * 128 + row) * 768 + k0 + c4);
      *(half4v*)&As[row][c4] = (half4v){f2h(va.x), f2h(va.y), f2h(va.z), f2h(va.w)};
      float4 vb = *(const float4*)(Wk + (size_t)(bn * 128 + row) * 768 + k0 + c4);
      *(half4v*)&Bs[row][c4] = (half4v){f2h(vb.x), f2h(vb.y), f2h(vb.z), f2h(vb.w)};
    }
    __syncthreads();
    for (int kk = 0; kk < 2; kk++) {
      half8 a[4], b[4];
      for (int mt = 0; mt < 4; mt++) a[mt] = *(half8*)&As[wm * 64 + mt * 16 + l15][kk * 32 + quad * 8];
      for (int nt = 0; nt < 4; nt++) b[nt] = *(half8*)&Bs[wn * 64 + nt * 16 + l15][kk * 32 + quad * 8];
      for (int mt = 0; mt < 4; mt++)
        for (int nt = 0; nt < 4; nt++)
          acc[mt * 4 + nt] = MFMA16(a[mt], b[nt], acc[mt * 4 + nt], 0, 0, 0);
    }
  }
  for (int mt = 0; mt < 4; mt++)
    for (int nt = 0; nt < 4; nt++) {
      int e = bn * 128 + wn * 64 + nt * 16 + l15;
      for (int r = 0; r < 4; r++) {
        int d = bm * 128 + wm * 64 + mt * 16 + quad * 4 + r;
        MT[(size_t)e * 768 + d] = acc[mt * 4 + nt][r];
      }
    }
}

// ---------------- WvT[e][d] = Wv[d][e], fp16 ----------------
__global__ void pack_wv_kernel(const float* __restrict__ Wv, _Float16* __restrict__ WvT) {
  __shared__ float tile[32][33];
  int k0 = blockIdx.x * 32;
  int n0 = blockIdx.y * 32;
  int tx = threadIdx.x, ty = threadIdx.y;
  for (int yy = ty; yy < 32; yy += 8)
    tile[yy][tx] = Wv[(size_t)(k0 + yy) * 768 + n0 + tx];
  __syncthreads();
  for (int yy = ty; yy < 32; yy += 8)
    WvT[(size_t)(n0 + yy) * 768 + k0 + tx] = f2h(tile[tx][yy]);
}

// ---------------- G = fp16(X * M) ----------------
__global__ __launch_bounds__(256) void proj_g_kernel(const float* __restrict__ X,
    const float* __restrict__ MT, _Float16* __restrict__ G) {
  __shared__ _Float16 As[128][72];
  __shared__ _Float16 Bs[128][72];
  int bn = blockIdx.x, bm = blockIdx.y;
  int tid = threadIdx.x, lane = tid & 63, wave = tid >> 6;
  int wm = wave >> 1, wn = wave & 1;
  int l15 = lane & 15, quad = lane >> 4;
  floatx4 acc[16];
  for (int i = 0; i < 16; i++) acc[i] = (floatx4){0.f, 0.f, 0.f, 0.f};
  for (int k0 = 0; k0 < 768; k0 += 64) {
    __syncthreads();
    for (int i = 0; i < 8; i++) {
      int f = i * 256 + tid;
      int row = f >> 4, c4 = (f & 15) << 2;
      float4 va = *(const float4*)(X + (size_t)(bm * 128 + row) * 768 + k0 + c4);
      *(half4v*)&As[row][c4] = (half4v){f2h(va.x), f2h(va.y), f2h(va.z), f2h(va.w)};
      float4 vb = *(const float4*)(MT + (size_t)(bn * 128 + row) * 768 + k0 + c4);
      *(half4v*)&Bs[row][c4] = (half4v){f2h(vb.x), f2h(vb.y), f2h(vb.z), f2h(vb.w)};
    }
    __syncthreads();
    for (int kk = 0; kk < 2; kk++) {
      half8 a[4], b[4];
      for (int mt = 0; mt < 4; mt++) a[mt] = *(half8*)&As[wm * 64 + mt * 16 + l15][kk * 32 + quad * 8];
      for (int nt = 0; nt < 4; nt++) b[nt] = *(half8*)&Bs[wn * 64 + nt * 16 + l15][kk * 32 + quad * 8];
      for (int mt = 0; mt < 4; mt++)
        for (int nt = 0; nt < 4; nt++)
          acc[mt * 4 + nt] = MFMA16(a[mt], b[nt], acc[mt * 4 + nt], 0, 0, 0);
    }
  }
  for (int mt = 0; mt < 4; mt++)
    for (int nt = 0; nt < 4; nt++) {
      int col = bn * 128 + wn * 64 + nt * 16 + l15;
      for (int r = 0; r < 4; r++) {
        int row = bm * 128 + wm * 64 + mt * 16 + quad * 4 + r;
        G[(size_t)row * 768 + col] = f2h(acc[mt * 4 + nt][r]);
      }
    }
}

// ---------------- Vt[b][d][n] = fp16(X * Wv)^T ----------------
__global__ __launch_bounds__(256) void proj_v_kernel(const float* __restrict__ X,
    const _Float16* __restrict__ WvT, _Float16* __restrict__ Vt) {
  __shared__ _Float16 As[128][72];
  __shared__ _Float16 Bs[128][72];
  int bn = blockIdx.x, bm = blockIdx.y;
  int tid = threadIdx.x, lane = tid & 63, wave = tid >> 6;
  int wm = wave >> 1, wn = wave & 1;
  int l15 = lane & 15, quad = lane >> 4;
  floatx4 acc[16];
  for (int i = 0; i < 16; i++) acc[i] = (floatx4){0.f, 0.f, 0.f, 0.f};
  for (int k0 = 0; k0 < 768; k0 += 64) {
    __syncthreads();
    for (int i = 0; i < 8; i++) {
      int f = i * 256 + tid;
      int row = f >> 4, c4 = (f & 15) << 2;
      float4 va = *(const float4*)(X + (size_t)(bm * 128 + row) * 768 + k0 + c4);
      *(half4v*)&As[row][c4] = (half4v){f2h(va.x), f2h(va.y), f2h(va.z), f2h(va.w)};
    }
    for (int i = 0; i < 4; i++) {
      int f = i * 256 + tid;
      int row = f >> 3, c8 = (f & 7) << 3;
      *(half8*)&Bs[row][c8] = *(const half8*)(WvT + (size_t)(bn * 128 + row) * 768 + k0 + c8);
    }
    __syncthreads();
    for (int kk = 0; kk < 2; kk++) {
      half8 a[4], b[4];
      for (int mt = 0; mt < 4; mt++) a[mt] = *(half8*)&As[wm * 64 + mt * 16 + l15][kk * 32 + quad * 8];
      for (int nt = 0; nt < 4; nt++) b[nt] = *(half8*)&Bs[wn * 64 + nt * 16 + l15][kk * 32 + quad * 8];
      for (int mt = 0; mt < 4; mt++)
        for (int nt = 0; nt < 4; nt++)
          acc[mt * 4 + nt] = MFMA16(a[mt], b[nt], acc[mt * 4 + nt], 0, 0, 0);
    }
  }
  for (int mt = 0; mt < 4; mt++)
    for (int nt = 0; nt < 4; nt++) {
      int d = bn * 128 + wn * 64 + nt * 16 + l15;
      int tok0 = bm * 128 + wm * 64 + mt * 16 + quad * 4;
      int bb = tok0 >> 11, ntok = tok0 & 2047;
      half4v p;
      for (int r = 0; r < 4; r++) p[r] = f2h(acc[mt * 4 + nt][r]);
      *(half4v*)(Vt + (size_t)(bb * 768 + d) * 2048 + ntok) = p;
    }
}

// ---------------- flash attention v3: 32 q/block, 128-key tiles, 2 barriers/iter ----------------
// S kept in registers; wave-reduced softmax (shfl_xor); exp in regs -> Pl (A-layout) direct.
// Wave w owns keys [w*32, w*32+32) for S, d-slice [w*192, w*192+192) for PV.
__global__ __launch_bounds__(256) void attn_kernel(const _Float16* __restrict__ G,
    const float* __restrict__ X, const _Float16* __restrict__ Vt, float* __restrict__ out) {
  __shared__ _Float16 Gs[32][776];   // 49,664 B
  __shared__ _Float16 Pl[32][136];   //  8,704 B
  __shared__ float pm[4][32];        // per-wave row maxes
  __shared__ float psum[4][32];      // per-wave row exp-sums
  __shared__ float m_run[32], l_run[32];

  int b = blockIdx.y;
  int q0 = blockIdx.x * 32;
  int tid = threadIdx.x;
  int lane = tid & 63, w = tid >> 6;
  int l15 = lane & 15, quad = lane >> 4;

  if (tid < 32) { m_run[tid] = -1e30f; l_run[tid] = 0.f; }

  floatx4 accO[24];   // [nt][sub]: 12 d-tiles x 2 q-subtiles
  for (int i = 0; i < 24; i++) accO[i] = (floatx4){0.f, 0.f, 0.f, 0.f};

  const _Float16* Gbase = G + (size_t)(b * 2048 + q0) * 768;
  const float*    Xkey  = X + (size_t)b * 2048 * 768;
  const _Float16* Vbase = Vt + (size_t)b * 768 * 2048;

  for (int i = 0; i < 12; i++) {
    int f = i * 256 + tid;
    int row = f / 96, c8 = (f % 96) * 8;
    *(half8*)&Gs[row][c8] = *(const half8*)(Gbase + (size_t)row * 768 + c8);
  }
  __syncthreads();

  for (int m0 = 0; m0 < 2048; m0 += 128) {
    // ======== S = G X^T : 32 q-rows x 128 keys; wave w: keys w*32..w*32+31 ========
    floatx4 sa[2][2];   // [slice][sub]
    for (int s = 0; s < 2; s++) for (int ss = 0; ss < 2; ss++) sa[s][ss] = (floatx4){0.f,0.f,0.f,0.f};
    const float* Kr0 = Xkey + (size_t)(m0 + w * 32 + l15) * 768 + quad * 8;
    const float* Kr1 = Kr0 + (size_t)16 * 768;
    // depth-2 unrolled prefetch: 8 float4 in flight
    float4 A0a = *(const float4*)Kr0,        A0c = *(const float4*)(Kr0 + 4);
    float4 A1a = *(const float4*)Kr1,        A1c = *(const float4*)(Kr1 + 4);
    float4 B0a = *(const float4*)(Kr0 + 32), B0c = *(const float4*)(Kr0 + 36);
    float4 B1a = *(const float4*)(Kr1 + 32), B1c = *(const float4*)(Kr1 + 36);
    #pragma unroll
    for (int kb = 0; kb < 24; kb += 2) {
      half8 qaE0 = *(half8*)&Gs[l15][kb * 32 + quad * 8];
      half8 qaE1 = *(half8*)&Gs[16 + l15][kb * 32 + quad * 8];
      half8 qaO0 = *(half8*)&Gs[l15][(kb + 1) * 32 + quad * 8];
      half8 qaO1 = *(half8*)&Gs[16 + l15][(kb + 1) * 32 + quad * 8];
      half8 kf0 = {f2h(A0a.x), f2h(A0a.y), f2h(A0a.z), f2h(A0a.w),
                   f2h(A0c.x), f2h(A0c.y), f2h(A0c.z), f2h(A0c.w)};
      half8 kf1 = {f2h(A1a.x), f2h(A1a.y), f2h(A1a.z), f2h(A1a.w),
                   f2h(A1c.x), f2h(A1c.y), f2h(A1c.z), f2h(A1c.w)};
      int o2 = (kb + 2 < 24) ? (kb + 2) * 32 : 0;
      A0a = *(const float4*)(Kr0 + o2); A0c = *(const float4*)(Kr0 + o2 + 4);
      A1a = *(const float4*)(Kr1 + o2); A1c = *(const float4*)(Kr1 + o2 + 4);
      sa[0][0] = MFMA16(qaE0, kf0, sa[0][0], 0, 0, 0);
      sa[0][1] = MFMA16(qaE1, kf0, sa[0][1], 0, 0, 0);
      sa[1][0] = MFMA16(qaE0, kf1, sa[1][0], 0, 0, 0);
      sa[1][1] = MFMA16(qaE1, kf1, sa[1][1], 0, 0, 0);
      half8 kg0 = {f2h(B0a.x), f2h(B0a.y), f2h(B0a.z), f2h(B0a.w),
                   f2h(B0c.x), f2h(B0c.y), f2h(B0c.z), f2h(B0c.w)};
      half8 kg1 = {f2h(B1a.x), f2h(B1a.y), f2h(B1a.z), f2h(B1a.w),
                   f2h(B1c.x), f2h(B1c.y), f2h(B1c.z), f2h(B1c.w)};
      int o3 = (kb + 3 < 24) ? (kb + 3) * 32 : 0;
      B0a = *(const float4*)(Kr0 + o3); B0c = *(const float4*)(Kr0 + o3 + 4);
      B1a = *(const float4*)(Kr1 + o3); B1c = *(const float4*)(Kr1 + o3 + 4);
      sa[0][0] = MFMA16(qaO0, kg0, sa[0][0], 0, 0, 0);
      sa[0][1] = MFMA16(qaO1, kg0, sa[0][1], 0, 0, 0);
      sa[1][0] = MFMA16(qaO0, kg1, sa[1][0], 0, 0, 0);
      sa[1][1] = MFMA16(qaO1, kg1, sa[1][1], 0, 0, 0);
    }
    // hoist ks=0 V loads (global, no LDS dependency) to cover PV startup latency
    const _Float16* vb_base0 = Vbase + (size_t)(w * 192 + l15) * 2048 + m0 + quad * 8;
    half8 vA = *(const half8*)vb_base0;
    half8 vB = *(const half8*)(vb_base0 + (size_t)16 * 2048);

    // ======== wave-local row max over this wave's 32 keys (shfl over 16 lanes) ========
    float mv[8];
    #pragma unroll
    for (int i = 0; i < 8; i++) {
      int ss = i >> 2, r = i & 3;
      mv[i] = fmaxf(sa[0][ss][r], sa[1][ss][r]);
    }
    #pragma unroll
    for (int mask = 1; mask <= 8; mask <<= 1)
      #pragma unroll
      for (int i = 0; i < 8; i++) mv[i] = fmaxf(mv[i], __shfl_xor(mv[i], mask));
    if (l15 == 0) {
      #pragma unroll
      for (int r = 0; r < 4; r++) { pm[w][quad * 4 + r] = mv[r]; pm[w][16 + quad * 4 + r] = mv[4 + r]; }
    }
    __syncthreads();   // barrier A: pm visible; m_run stable (old)
    // ======== all threads: combine wave maxes (broadcast reads, idempotent) ========
    float mnew[8], alpha[8];
    #pragma unroll
    for (int i = 0; i < 8; i++) {
      int row = (i >> 2) * 16 + quad * 4 + (i & 3);
      float mo = m_run[row];
      float mn = mo;
      #pragma unroll
      for (int w2 = 0; w2 < 4; w2++) mn = fmaxf(mn, pm[w2][row]);
      mnew[i] = mn;
      alpha[i] = __expf(mo - mn);
    }
    // ======== exp in regs -> Pl (A-layout), row partial sums ========
    float pr[8];
    #pragma unroll
    for (int i = 0; i < 8; i++) pr[i] = 0.f;
    #pragma unroll
    for (int s = 0; s < 2; s++)
      #pragma unroll
      for (int i = 0; i < 8; i++) {
        int ss = i >> 2, r = i & 3;
        int row = ss * 16 + quad * 4 + r;
        float p = __expf(sa[s][ss][r] - mnew[i]);
        pr[i] += p;
        Pl[row][w * 32 + s * 16 + l15] = f2h(p);
      }
    #pragma unroll
    for (int mask = 1; mask <= 8; mask <<= 1)
      #pragma unroll
      for (int i = 0; i < 8; i++) pr[i] += __shfl_xor(pr[i], mask);
    if (l15 == 0) {
      #pragma unroll
      for (int r = 0; r < 4; r++) { psum[w][quad * 4 + r] = pr[r]; psum[w][16 + quad * 4 + r] = pr[4 + r]; }
    }
    // rescale O while Pl/psum settle
    #pragma unroll
    for (int nt = 0; nt < 12; nt++)
      #pragma unroll
      for (int i = 0; i < 8; i++)
        accO[nt * 2 + (i >> 2)][i & 3] *= alpha[i];
    __syncthreads();   // barrier B: Pl + psum visible
    if (w == 0 && l15 == 0) {   // fold running stats (concurrent with PV on other lanes)
      #pragma unroll
      for (int i = 0; i < 8; i++) {
        int row = (i >> 2) * 16 + quad * 4 + (i & 3);
        l_run[row] = l_run[row] * alpha[i] + (psum[0][row] + psum[1][row] + psum[2][row] + psum[3][row]);
        m_run[row] = mnew[i];
      }
    }
    // ======== O += P V : wave w owns d-slice w*192..+191, K=128 keys ========
    #pragma unroll
    for (int ks = 0; ks < 4; ks++) {
      half8 pa0 = *(half8*)&Pl[l15][ks * 32 + quad * 8];
      half8 pa1 = *(half8*)&Pl[16 + l15][ks * 32 + quad * 8];
      const _Float16* vb_base = vb_base0 + ks * 32;
      #pragma unroll
      for (int nt = 0; nt < 12; nt += 2) {
        half8 vC = (nt + 2 < 12) ? *(const half8*)(vb_base + (size_t)(nt + 2) * 16 * 2048)
                                 : *(const half8*)(vb_base0 + (ks + 1 < 4 ? (ks + 1) * 32 : 0));
        accO[nt * 2 + 0] = MFMA16(pa0, vA, accO[nt * 2 + 0], 0, 0, 0);
        accO[nt * 2 + 1] = MFMA16(pa1, vA, accO[nt * 2 + 1], 0, 0, 0);
        half8 vD = (nt + 3 < 12) ? *(const half8*)(vb_base + (size_t)(nt + 3) * 16 * 2048)
                                 : *(const half8*)(vb_base0 + (size_t)16 * 2048 + (ks + 1 < 4 ? (ks + 1) * 32 : 0));
        accO[(nt + 1) * 2 + 0] = MFMA16(pa0, vB, accO[(nt + 1) * 2 + 0], 0, 0, 0);
        accO[(nt + 1) * 2 + 1] = MFMA16(pa1, vB, accO[(nt + 1) * 2 + 1], 0, 0, 0);
        vA = vC; vB = vD;
      }
    }
  }
  __syncthreads();   // l_run final visible
  float il[8];
  #pragma unroll
  for (int i = 0; i < 8; i++) {
    int row = (i >> 2) * 16 + quad * 4 + (i & 3);
    il[i] = 1.f / l_run[row];
  }
  #pragma unroll
  for (int nt = 0; nt < 12; nt++)
    #pragma unroll
    for (int ss = 0; ss < 2; ss++) {
      int d = w * 192 + nt * 16 + l15;
      #pragma unroll
      for (int r = 0; r < 4; r++) {
        int row = q0 + ss * 16 + quad * 4 + r;
        out[(size_t)(b * 2048 + row) * 768 + d] = accO[nt * 2 + ss][r] * il[ss * 4 + r];
      }
    }
}

extern "C" void kernel_launch(void* const* d_in, const int* in_sizes, int n_in,
                              void* d_out, int out_size, void* d_ws, size_t ws_size,
                              hipStream_t stream) {
  (void)in_sizes; (void)n_in; (void)out_size; (void)ws_size;
  const float* X  = (const float*)d_in[0];
  const float* Wq = (const float*)d_in[1];
  const float* Wk = (const float*)d_in[2];
  const float* Wv = (const float*)d_in[3];
  float* out = (float*)d_out;

  char* ws = (char*)d_ws;
  _Float16* G  = (_Float16*)ws;                        // 25,165,824 B
  _Float16* Vt = (_Float16*)(ws + 25165824);           // 25,165,824 B

  float*    MT  = (float*)d_out;                       // scratch in out
  _Float16* WvT = (_Float16*)((char*)d_out + 2359296); // scratch in out

  mm_small_kernel<<<dim3(6, 6), 256, 0, stream>>>(Wq, Wk, MT);
  pack_wv_kernel<<<dim3(24, 24), dim3(32, 8), 0, stream>>>(Wv, WvT);
  proj_g_kernel<<<dim3(6, 128), 256, 0, stream>>>(X, MT, G);
  proj_v_kernel<<<dim3(6, 128), 256, 0, stream>>>(X, WvT, Vt);
  attn_kernel<<<dim3(64, 8), 256, 0, stream>>>(G, X, Vt, out);
}

// Round 4
// 648.068 us; speedup vs baseline: 1.2380x; 1.2380x over previous
//
#include <hip/hip_runtime.h>

// B=8, N=2048, D=F=768. out = softmax((X Wq)(X Wk)^T) (X Wv), fp32 I/O.
// Identity: S[q][k] = sum_d X[q][d] * H[k][d],  H = X * M^T,  M = Wq Wk^T.
//   -> queries read from X directly (tiny), keys = H rows (fp16, k-contiguous).
// ws: H = fp16(X M^T) [16384][768] | Vt = fp16(X Wv)^T [8][768][2048]  (50,331,648 B)
// d_out scratch (consumed before attn writes out): M fp32 row-major, WvT fp16.

typedef __attribute__((ext_vector_type(8))) _Float16 half8;
typedef __attribute__((ext_vector_type(4))) _Float16 half4v;
typedef __attribute__((ext_vector_type(4))) float floatx4;

__device__ __forceinline__ _Float16 f2h(float f) { return (_Float16)f; }
#define MFMA16 __builtin_amdgcn_mfma_f32_16x16x32_f16

// ---------------- M[d][e] = (Wq Wk^T), fp32 row-major ----------------
__global__ __launch_bounds__(256) void mm_small_kernel(const float* __restrict__ Wq,
    const float* __restrict__ Wk, float* __restrict__ M) {
  __shared__ _Float16 As[128][72];
  __shared__ _Float16 Bs[128][72];
  int bn = blockIdx.x, bm = blockIdx.y;
  int tid = threadIdx.x, lane = tid & 63, wave = tid >> 6;
  int wm = wave >> 1, wn = wave & 1;
  int l15 = lane & 15, quad = lane >> 4;
  floatx4 acc[16];
  for (int i = 0; i < 16; i++) acc[i] = (floatx4){0.f, 0.f, 0.f, 0.f};
  for (int k0 = 0; k0 < 768; k0 += 64) {
    __syncthreads();
    for (int i = 0; i < 8; i++) {
      int f = i * 256 + tid;
      int row = f >> 4, c4 = (f & 15) << 2;
      float4 va = *(const float4*)(Wq + (size_t)(bm * 128 + row) * 768 + k0 + c4);
      *(half4v*)&As[row][c4] = (half4v){f2h(va.x), f2h(va.y), f2h(va.z), f2h(va.w)};
      float4 vb = *(const float4*)(Wk + (size_t)(bn * 128 + row) * 768 + k0 + c4);
      *(half4v*)&Bs[row][c4] = (half4v){f2h(vb.x), f2h(vb.y), f2h(vb.z), f2h(vb.w)};
    }
    __syncthreads();
    for (int kk = 0; kk < 2; kk++) {
      half8 a[4], b[4];
      for (int mt = 0; mt < 4; mt++) a[mt] = *(half8*)&As[wm * 64 + mt * 16 + l15][kk * 32 + quad * 8];
      for (int nt = 0; nt < 4; nt++) b[nt] = *(half8*)&Bs[wn * 64 + nt * 16 + l15][kk * 32 + quad * 8];
      for (int mt = 0; mt < 4; mt++)
        for (int nt = 0; nt < 4; nt++)
          acc[mt * 4 + nt] = MFMA16(a[mt], b[nt], acc[mt * 4 + nt], 0, 0, 0);
    }
  }
  for (int mt = 0; mt < 4; mt++)
    for (int nt = 0; nt < 4; nt++) {
      int e = bn * 128 + wn * 64 + nt * 16 + l15;
      for (int r = 0; r < 4; r++) {
        int d = bm * 128 + wm * 64 + mt * 16 + quad * 4 + r;
        M[(size_t)d * 768 + e] = acc[mt * 4 + nt][r];   // plain row-major store
      }
    }
}

// ---------------- WvT[e][d] = Wv[d][e], fp16 ----------------
__global__ void pack_wv_kernel(const float* __restrict__ Wv, _Float16* __restrict__ WvT) {
  __shared__ float tile[32][33];
  int k0 = blockIdx.x * 32;
  int n0 = blockIdx.y * 32;
  int tx = threadIdx.x, ty = threadIdx.y;
  for (int yy = ty; yy < 32; yy += 8)
    tile[yy][tx] = Wv[(size_t)(k0 + yy) * 768 + n0 + tx];
  __syncthreads();
  for (int yy = ty; yy < 32; yy += 8)
    WvT[(size_t)(n0 + yy) * 768 + k0 + tx] = f2h(tile[tx][yy]);
}

// ---------------- H = fp16(X * M^T): A = X rows, B[n=e][k=d] = M[e][d] ----------------
__global__ __launch_bounds__(256) void proj_h_kernel(const float* __restrict__ X,
    const float* __restrict__ M, _Float16* __restrict__ H) {
  __shared__ _Float16 As[128][72];
  __shared__ _Float16 Bs[128][72];
  int bn = blockIdx.x, bm = blockIdx.y;
  int tid = threadIdx.x, lane = tid & 63, wave = tid >> 6;
  int wm = wave >> 1, wn = wave & 1;
  int l15 = lane & 15, quad = lane >> 4;
  floatx4 acc[16];
  for (int i = 0; i < 16; i++) acc[i] = (floatx4){0.f, 0.f, 0.f, 0.f};
  for (int k0 = 0; k0 < 768; k0 += 64) {
    __syncthreads();
    for (int i = 0; i < 8; i++) {
      int f = i * 256 + tid;
      int row = f >> 4, c4 = (f & 15) << 2;
      float4 va = *(const float4*)(X + (size_t)(bm * 128 + row) * 768 + k0 + c4);
      *(half4v*)&As[row][c4] = (half4v){f2h(va.x), f2h(va.y), f2h(va.z), f2h(va.w)};
      float4 vb = *(const float4*)(M + (size_t)(bn * 128 + row) * 768 + k0 + c4);
      *(half4v*)&Bs[row][c4] = (half4v){f2h(vb.x), f2h(vb.y), f2h(vb.z), f2h(vb.w)};
    }
    __syncthreads();
    for (int kk = 0; kk < 2; kk++) {
      half8 a[4], b[4];
      for (int mt = 0; mt < 4; mt++) a[mt] = *(half8*)&As[wm * 64 + mt * 16 + l15][kk * 32 + quad * 8];
      for (int nt = 0; nt < 4; nt++) b[nt] = *(half8*)&Bs[wn * 64 + nt * 16 + l15][kk * 32 + quad * 8];
      for (int mt = 0; mt < 4; mt++)
        for (int nt = 0; nt < 4; nt++)
          acc[mt * 4 + nt] = MFMA16(a[mt], b[nt], acc[mt * 4 + nt], 0, 0, 0);
    }
  }
  for (int mt = 0; mt < 4; mt++)
    for (int nt = 0; nt < 4; nt++) {
      int col = bn * 128 + wn * 64 + nt * 16 + l15;
      for (int r = 0; r < 4; r++) {
        int row = bm * 128 + wm * 64 + mt * 16 + quad * 4 + r;
        H[(size_t)row * 768 + col] = f2h(acc[mt * 4 + nt][r]);
      }
    }
}

// ---------------- Vt[b][d][n] = fp16(X * Wv)^T ----------------
__global__ __launch_bounds__(256) void proj_v_kernel(const float* __restrict__ X,
    const _Float16* __restrict__ WvT, _Float16* __restrict__ Vt) {
  __shared__ _Float16 As[128][72];
  __shared__ _Float16 Bs[128][72];
  int bn = blockIdx.x, bm = blockIdx.y;
  int tid = threadIdx.x, lane = tid & 63, wave = tid >> 6;
  int wm = wave >> 1, wn = wave & 1;
  int l15 = lane & 15, quad = lane >> 4;
  floatx4 acc[16];
  for (int i = 0; i < 16; i++) acc[i] = (floatx4){0.f, 0.f, 0.f, 0.f};
  for (int k0 = 0; k0 < 768; k0 += 64) {
    __syncthreads();
    for (int i = 0; i < 8; i++) {
      int f = i * 256 + tid;
      int row = f >> 4, c4 = (f & 15) << 2;
      float4 va = *(const float4*)(X + (size_t)(bm * 128 + row) * 768 + k0 + c4);
      *(half4v*)&As[row][c4] = (half4v){f2h(va.x), f2h(va.y), f2h(va.z), f2h(va.w)};
    }
    for (int i = 0; i < 4; i++) {
      int f = i * 256 + tid;
      int row = f >> 3, c8 = (f & 7) << 3;
      *(half8*)&Bs[row][c8] = *(const half8*)(WvT + (size_t)(bn * 128 + row) * 768 + k0 + c8);
    }
    __syncthreads();
    for (int kk = 0; kk < 2; kk++) {
      half8 a[4], b[4];
      for (int mt = 0; mt < 4; mt++) a[mt] = *(half8*)&As[wm * 64 + mt * 16 + l15][kk * 32 + quad * 8];
      for (int nt = 0; nt < 4; nt++) b[nt] = *(half8*)&Bs[wn * 64 + nt * 16 + l15][kk * 32 + quad * 8];
      for (int mt = 0; mt < 4; mt++)
        for (int nt = 0; nt < 4; nt++)
          acc[mt * 4 + nt] = MFMA16(a[mt], b[nt], acc[mt * 4 + nt], 0, 0, 0);
    }
  }
  for (int mt = 0; mt < 4; mt++)
    for (int nt = 0; nt < 4; nt++) {
      int d = bn * 128 + wn * 64 + nt * 16 + l15;
      int tok0 = bm * 128 + wm * 64 + mt * 16 + quad * 4;
      int bb = tok0 >> 11, ntok = tok0 & 2047;
      half4v p;
      for (int r = 0; r < 4; r++) p[r] = f2h(acc[mt * 4 + nt][r]);
      *(half4v*)(Vt + (size_t)(bb * 768 + d) * 2048 + ntok) = p;
    }
}

// ---------------- flash attention v4: fp16 keys (H), batch->XCD swizzle ----------------
// 32 q/block, 128-key tiles; wave w: keys [w*32,+32) for S, d-slice [w*192,+192) for PV.
__global__ __launch_bounds__(256) void attn_kernel(const _Float16* __restrict__ H,
    const float* __restrict__ X, const _Float16* __restrict__ Vt, float* __restrict__ out) {
  __shared__ _Float16 Qs[32][776];   // 49,664 B — fp16 queries
  __shared__ _Float16 Pl[32][136];   //  8,704 B
  __shared__ float pm[4][32];
  __shared__ float psum[4][32];
  __shared__ float m_run[32], l_run[32];

  int id = blockIdx.x;
  int b = id & 7;          // batch -> XCD (round-robin %8 dispatch heuristic)
  int q0 = (id >> 3) * 32;
  int tid = threadIdx.x;
  int lane = tid & 63, w = tid >> 6;
  int l15 = lane & 15, quad = lane >> 4;

  if (tid < 32) { m_run[tid] = -1e30f; l_run[tid] = 0.f; }

  floatx4 accO[24];
  for (int i = 0; i < 24; i++) accO[i] = (floatx4){0.f, 0.f, 0.f, 0.f};

  const float*    Xq    = X + (size_t)(b * 2048 + q0) * 768;
  const _Float16* Hbase = H + (size_t)(b * 2048) * 768;
  const _Float16* Vbase = Vt + (size_t)b * 768 * 2048;

  // stage queries: X fp32 -> Qs fp16 (32 x 768)
  for (int i = 0; i < 12; i++) {
    int f = i * 256 + tid;
    int row = f / 96, c8 = (f % 96) * 8;
    float4 a = *(const float4*)(Xq + (size_t)row * 768 + c8);
    float4 c = *(const float4*)(Xq + (size_t)row * 768 + c8 + 4);
    *(half8*)&Qs[row][c8] = (half8){f2h(a.x), f2h(a.y), f2h(a.z), f2h(a.w),
                                    f2h(c.x), f2h(c.y), f2h(c.z), f2h(c.w)};
  }
  __syncthreads();

  for (int m0 = 0; m0 < 2048; m0 += 128) {
    // ======== S = Q H^T : 32 q-rows x 128 keys; wave w: keys w*32..+31 ========
    floatx4 sa[2][2];
    for (int s = 0; s < 2; s++) for (int ss = 0; ss < 2; ss++) sa[s][ss] = (floatx4){0.f,0.f,0.f,0.f};
    const _Float16* Kr0 = Hbase + (size_t)(m0 + w * 32 + l15) * 768 + quad * 8;
    const _Float16* Kr1 = Kr0 + (size_t)16 * 768;
    // rolling prefetch: 8 half8 in flight (4 kb of lookahead)
    half8 kA0 = *(const half8*)Kr0,        kA1 = *(const half8*)Kr1;
    half8 kB0 = *(const half8*)(Kr0 + 32), kB1 = *(const half8*)(Kr1 + 32);
    half8 kC0 = *(const half8*)(Kr0 + 64), kC1 = *(const half8*)(Kr1 + 64);
    half8 kD0 = *(const half8*)(Kr0 + 96), kD1 = *(const half8*)(Kr1 + 96);
    #pragma unroll
    for (int kb = 0; kb < 24; kb += 2) {
      half8 qaE0 = *(half8*)&Qs[l15][kb * 32 + quad * 8];
      half8 qaE1 = *(half8*)&Qs[16 + l15][kb * 32 + quad * 8];
      half8 qaO0 = *(half8*)&Qs[l15][(kb + 1) * 32 + quad * 8];
      half8 qaO1 = *(half8*)&Qs[16 + l15][(kb + 1) * 32 + quad * 8];
      int o4 = (kb + 4 < 24) ? (kb + 4) * 32 : 0;
      int o5 = (kb + 5 < 24) ? (kb + 5) * 32 : 0;
      sa[0][0] = MFMA16(qaE0, kA0, sa[0][0], 0, 0, 0);
      sa[0][1] = MFMA16(qaE1, kA0, sa[0][1], 0, 0, 0);
      sa[1][0] = MFMA16(qaE0, kA1, sa[1][0], 0, 0, 0);
      sa[1][1] = MFMA16(qaE1, kA1, sa[1][1], 0, 0, 0);
      kA0 = kC0; kA1 = kC1;
      kC0 = *(const half8*)(Kr0 + o4); kC1 = *(const half8*)(Kr1 + o4);
      sa[0][0] = MFMA16(qaO0, kB0, sa[0][0], 0, 0, 0);
      sa[0][1] = MFMA16(qaO1, kB0, sa[0][1], 0, 0, 0);
      sa[1][0] = MFMA16(qaO0, kB1, sa[1][0], 0, 0, 0);
      sa[1][1] = MFMA16(qaO1, kB1, sa[1][1], 0, 0, 0);
      kB0 = kD0; kB1 = kD1;
      kD0 = *(const half8*)(Kr0 + o5); kD1 = *(const half8*)(Kr1 + o5);
    }
    // hoist first PV V loads
    const _Float16* vb_base0 = Vbase + (size_t)(w * 192 + l15) * 2048 + m0 + quad * 8;
    half8 vA = *(const half8*)vb_base0;
    half8 vB = *(const half8*)(vb_base0 + (size_t)16 * 2048);

    // ======== wave-local row max (shfl over 16 lanes) ========
    float mv[8];
    #pragma unroll
    for (int i = 0; i < 8; i++) {
      int ss = i >> 2, r = i & 3;
      mv[i] = fmaxf(sa[0][ss][r], sa[1][ss][r]);
    }
    #pragma unroll
    for (int mask = 1; mask <= 8; mask <<= 1)
      #pragma unroll
      for (int i = 0; i < 8; i++) mv[i] = fmaxf(mv[i], __shfl_xor(mv[i], mask));
    if (l15 == 0) {
      #pragma unroll
      for (int r = 0; r < 4; r++) { pm[w][quad * 4 + r] = mv[r]; pm[w][16 + quad * 4 + r] = mv[4 + r]; }
    }
    __syncthreads();   // barrier A
    float mnew[8], alpha[8];
    #pragma unroll
    for (int i = 0; i < 8; i++) {
      int row = (i >> 2) * 16 + quad * 4 + (i & 3);
      float mo = m_run[row];
      float mn = mo;
      #pragma unroll
      for (int w2 = 0; w2 < 4; w2++) mn = fmaxf(mn, pm[w2][row]);
      mnew[i] = mn;
      alpha[i] = __expf(mo - mn);
    }
    float pr[8];
    #pragma unroll
    for (int i = 0; i < 8; i++) pr[i] = 0.f;
    #pragma unroll
    for (int s = 0; s < 2; s++)
      #pragma unroll
      for (int i = 0; i < 8; i++) {
        int ss = i >> 2, r = i & 3;
        int row = ss * 16 + quad * 4 + r;
        float p = __expf(sa[s][ss][r] - mnew[i]);
        pr[i] += p;
        Pl[row][w * 32 + s * 16 + l15] = f2h(p);
      }
    #pragma unroll
    for (int mask = 1; mask <= 8; mask <<= 1)
      #pragma unroll
      for (int i = 0; i < 8; i++) pr[i] += __shfl_xor(pr[i], mask);
    if (l15 == 0) {
      #pragma unroll
      for (int r = 0; r < 4; r++) { psum[w][quad * 4 + r] = pr[r]; psum[w][16 + quad * 4 + r] = pr[4 + r]; }
    }
    #pragma unroll
    for (int nt = 0; nt < 12; nt++)
      #pragma unroll
      for (int i = 0; i < 8; i++)
        accO[nt * 2 + (i >> 2)][i & 3] *= alpha[i];
    __syncthreads();   // barrier B
    if (w == 0 && l15 == 0) {
      #pragma unroll
      for (int i = 0; i < 8; i++) {
        int row = (i >> 2) * 16 + quad * 4 + (i & 3);
        l_run[row] = l_run[row] * alpha[i] + (psum[0][row] + psum[1][row] + psum[2][row] + psum[3][row]);
        m_run[row] = mnew[i];
      }
    }
    // ======== O += P V ========
    #pragma unroll
    for (int ks = 0; ks < 4; ks++) {
      half8 pa0 = *(half8*)&Pl[l15][ks * 32 + quad * 8];
      half8 pa1 = *(half8*)&Pl[16 + l15][ks * 32 + quad * 8];
      const _Float16* vb_base = vb_base0 + ks * 32;
      #pragma unroll
      for (int nt = 0; nt < 12; nt += 2) {
        half8 vC = (nt + 2 < 12) ? *(const half8*)(vb_base + (size_t)(nt + 2) * 16 * 2048)
                                 : *(const half8*)(vb_base0 + (ks + 1 < 4 ? (ks + 1) * 32 : 0));
        accO[nt * 2 + 0] = MFMA16(pa0, vA, accO[nt * 2 + 0], 0, 0, 0);
        accO[nt * 2 + 1] = MFMA16(pa1, vA, accO[nt * 2 + 1], 0, 0, 0);
        half8 vD = (nt + 3 < 12) ? *(const half8*)(vb_base + (size_t)(nt + 3) * 16 * 2048)
                                 : *(const half8*)(vb_base0 + (size_t)16 * 2048 + (ks + 1 < 4 ? (ks + 1) * 32 : 0));
        accO[(nt + 1) * 2 + 0] = MFMA16(pa0, vB, accO[(nt + 1) * 2 + 0], 0, 0, 0);
        accO[(nt + 1) * 2 + 1] = MFMA16(pa1, vB, accO[(nt + 1) * 2 + 1], 0, 0, 0);
        vA = vC; vB = vD;
      }
    }
  }
  __syncthreads();
  float il[8];
  #pragma unroll
  for (int i = 0; i < 8; i++) {
    int row = (i >> 2) * 16 + quad * 4 + (i & 3);
    il[i] = 1.f / l_run[row];
  }
  #pragma unroll
  for (int nt = 0; nt < 12; nt++)
    #pragma unroll
    for (int ss = 0; ss < 2; ss++) {
      int d = w * 192 + nt * 16 + l15;
      #pragma unroll
      for (int r = 0; r < 4; r++) {
        int row = q0 + ss * 16 + quad * 4 + r;
        out[(size_t)(b * 2048 + row) * 768 + d] = accO[nt * 2 + ss][r] * il[ss * 4 + r];
      }
    }
}

extern "C" void kernel_launch(void* const* d_in, const int* in_sizes, int n_in,
                              void* d_out, int out_size, void* d_ws, size_t ws_size,
                              hipStream_t stream) {
  (void)in_sizes; (void)n_in; (void)out_size; (void)ws_size;
  const float* X  = (const float*)d_in[0];
  const float* Wq = (const float*)d_in[1];
  const float* Wk = (const float*)d_in[2];
  const float* Wv = (const float*)d_in[3];
  float* out = (float*)d_out;

  char* ws = (char*)d_ws;
  _Float16* H  = (_Float16*)ws;                        // 25,165,824 B
  _Float16* Vt = (_Float16*)(ws + 25165824);           // 25,165,824 B

  float*    M   = (float*)d_out;                       // scratch in out (fp32 768x768)
  _Float16* WvT = (_Float16*)((char*)d_out + 2359296); // scratch in out

  mm_small_kernel<<<dim3(6, 6), 256, 0, stream>>>(Wq, Wk, M);
  pack_wv_kernel<<<dim3(24, 24), dim3(32, 8), 0, stream>>>(Wv, WvT);
  proj_h_kernel<<<dim3(6, 128), 256, 0, stream>>>(X, M, H);
  proj_v_kernel<<<dim3(6, 128), 256, 0, stream>>>(X, WvT, Vt);
  attn_kernel<<<512, 256, 0, stream>>>(H, X, Vt, out);
}

// Round 5
// 607.437 us; speedup vs baseline: 1.3209x; 1.0669x over previous
//
#include <hip/hip_runtime.h>

// B=8, N=2048, D=F=768. out = softmax((X Wq)(X Wk)^T) (X Wv), fp32 I/O.
// Identity: S[q][k] = sum_d X[q][d] * H[k][d],  H = X * M^T,  M = Wq Wk^T.
// ws: H = fp16(X M^T) [16384][768] | Vt = fp16(X Wv)^T [8][768][2048]  (50,331,648 B)
// d_out scratch (consumed before attn writes out): M fp32 row-major, WvT fp16.
// attn v5: 512 thr / 8 waves per block; wave w: 16-key slice (S), 96-d slice (PV).
//   -> 16 waves/CU (4/SIMD) for latency hiding; traffic identical to v4.

typedef __attribute__((ext_vector_type(8))) _Float16 half8;
typedef __attribute__((ext_vector_type(4))) _Float16 half4v;
typedef __attribute__((ext_vector_type(4))) float floatx4;

__device__ __forceinline__ _Float16 f2h(float f) { return (_Float16)f; }
#define MFMA16 __builtin_amdgcn_mfma_f32_16x16x32_f16

// ---------------- M[d][e] = (Wq Wk^T), fp32 row-major ----------------
__global__ __launch_bounds__(256) void mm_small_kernel(const float* __restrict__ Wq,
    const float* __restrict__ Wk, float* __restrict__ M) {
  __shared__ _Float16 As[128][72];
  __shared__ _Float16 Bs[128][72];
  int bn = blockIdx.x, bm = blockIdx.y;
  int tid = threadIdx.x, lane = tid & 63, wave = tid >> 6;
  int wm = wave >> 1, wn = wave & 1;
  int l15 = lane & 15, quad = lane >> 4;
  floatx4 acc[16];
  for (int i = 0; i < 16; i++) acc[i] = (floatx4){0.f, 0.f, 0.f, 0.f};
  for (int k0 = 0; k0 < 768; k0 += 64) {
    __syncthreads();
    for (int i = 0; i < 8; i++) {
      int f = i * 256 + tid;
      int row = f >> 4, c4 = (f & 15) << 2;
      float4 va = *(const float4*)(Wq + (size_t)(bm * 128 + row) * 768 + k0 + c4);
      *(half4v*)&As[row][c4] = (half4v){f2h(va.x), f2h(va.y), f2h(va.z), f2h(va.w)};
      float4 vb = *(const float4*)(Wk + (size_t)(bn * 128 + row) * 768 + k0 + c4);
      *(half4v*)&Bs[row][c4] = (half4v){f2h(vb.x), f2h(vb.y), f2h(vb.z), f2h(vb.w)};
    }
    __syncthreads();
    for (int kk = 0; kk < 2; kk++) {
      half8 a[4], b[4];
      for (int mt = 0; mt < 4; mt++) a[mt] = *(half8*)&As[wm * 64 + mt * 16 + l15][kk * 32 + quad * 8];
      for (int nt = 0; nt < 4; nt++) b[nt] = *(half8*)&Bs[wn * 64 + nt * 16 + l15][kk * 32 + quad * 8];
      for (int mt = 0; mt < 4; mt++)
        for (int nt = 0; nt < 4; nt++)
          acc[mt * 4 + nt] = MFMA16(a[mt], b[nt], acc[mt * 4 + nt], 0, 0, 0);
    }
  }
  for (int mt = 0; mt < 4; mt++)
    for (int nt = 0; nt < 4; nt++) {
      int e = bn * 128 + wn * 64 + nt * 16 + l15;
      for (int r = 0; r < 4; r++) {
        int d = bm * 128 + wm * 64 + mt * 16 + quad * 4 + r;
        M[(size_t)d * 768 + e] = acc[mt * 4 + nt][r];
      }
    }
}

// ---------------- WvT[e][d] = Wv[d][e], fp16 ----------------
__global__ void pack_wv_kernel(const float* __restrict__ Wv, _Float16* __restrict__ WvT) {
  __shared__ float tile[32][33];
  int k0 = blockIdx.x * 32;
  int n0 = blockIdx.y * 32;
  int tx = threadIdx.x, ty = threadIdx.y;
  for (int yy = ty; yy < 32; yy += 8)
    tile[yy][tx] = Wv[(size_t)(k0 + yy) * 768 + n0 + tx];
  __syncthreads();
  for (int yy = ty; yy < 32; yy += 8)
    WvT[(size_t)(n0 + yy) * 768 + k0 + tx] = f2h(tile[tx][yy]);
}

// ---------------- H = fp16(X * M^T) ----------------
__global__ __launch_bounds__(256) void proj_h_kernel(const float* __restrict__ X,
    const float* __restrict__ M, _Float16* __restrict__ H) {
  __shared__ _Float16 As[128][72];
  __shared__ _Float16 Bs[128][72];
  int bn = blockIdx.x, bm = blockIdx.y;
  int tid = threadIdx.x, lane = tid & 63, wave = tid >> 6;
  int wm = wave >> 1, wn = wave & 1;
  int l15 = lane & 15, quad = lane >> 4;
  floatx4 acc[16];
  for (int i = 0; i < 16; i++) acc[i] = (floatx4){0.f, 0.f, 0.f, 0.f};
  for (int k0 = 0; k0 < 768; k0 += 64) {
    __syncthreads();
    for (int i = 0; i < 8; i++) {
      int f = i * 256 + tid;
      int row = f >> 4, c4 = (f & 15) << 2;
      float4 va = *(const float4*)(X + (size_t)(bm * 128 + row) * 768 + k0 + c4);
      *(half4v*)&As[row][c4] = (half4v){f2h(va.x), f2h(va.y), f2h(va.z), f2h(va.w)};
      float4 vb = *(const float4*)(M + (size_t)(bn * 128 + row) * 768 + k0 + c4);
      *(half4v*)&Bs[row][c4] = (half4v){f2h(vb.x), f2h(vb.y), f2h(vb.z), f2h(vb.w)};
    }
    __syncthreads();
    for (int kk = 0; kk < 2; kk++) {
      half8 a[4], b[4];
      for (int mt = 0; mt < 4; mt++) a[mt] = *(half8*)&As[wm * 64 + mt * 16 + l15][kk * 32 + quad * 8];
      for (int nt = 0; nt < 4; nt++) b[nt] = *(half8*)&Bs[wn * 64 + nt * 16 + l15][kk * 32 + quad * 8];
      for (int mt = 0; mt < 4; mt++)
        for (int nt = 0; nt < 4; nt++)
          acc[mt * 4 + nt] = MFMA16(a[mt], b[nt], acc[mt * 4 + nt], 0, 0, 0);
    }
  }
  for (int mt = 0; mt < 4; mt++)
    for (int nt = 0; nt < 4; nt++) {
      int col = bn * 128 + wn * 64 + nt * 16 + l15;
      for (int r = 0; r < 4; r++) {
        int row = bm * 128 + wm * 64 + mt * 16 + quad * 4 + r;
        H[(size_t)row * 768 + col] = f2h(acc[mt * 4 + nt][r]);
      }
    }
}

// ---------------- Vt[b][d][n] = fp16(X * Wv)^T ----------------
__global__ __launch_bounds__(256) void proj_v_kernel(const float* __restrict__ X,
    const _Float16* __restrict__ WvT, _Float16* __restrict__ Vt) {
  __shared__ _Float16 As[128][72];
  __shared__ _Float16 Bs[128][72];
  int bn = blockIdx.x, bm = blockIdx.y;
  int tid = threadIdx.x, lane = tid & 63, wave = tid >> 6;
  int wm = wave >> 1, wn = wave & 1;
  int l15 = lane & 15, quad = lane >> 4;
  floatx4 acc[16];
  for (int i = 0; i < 16; i++) acc[i] = (floatx4){0.f, 0.f, 0.f, 0.f};
  for (int k0 = 0; k0 < 768; k0 += 64) {
    __syncthreads();
    for (int i = 0; i < 8; i++) {
      int f = i * 256 + tid;
      int row = f >> 4, c4 = (f & 15) << 2;
      float4 va = *(const float4*)(X + (size_t)(bm * 128 + row) * 768 + k0 + c4);
      *(half4v*)&As[row][c4] = (half4v){f2h(va.x), f2h(va.y), f2h(va.z), f2h(va.w)};
    }
    for (int i = 0; i < 4; i++) {
      int f = i * 256 + tid;
      int row = f >> 3, c8 = (f & 7) << 3;
      *(half8*)&Bs[row][c8] = *(const half8*)(WvT + (size_t)(bn * 128 + row) * 768 + k0 + c8);
    }
    __syncthreads();
    for (int kk = 0; kk < 2; kk++) {
      half8 a[4], b[4];
      for (int mt = 0; mt < 4; mt++) a[mt] = *(half8*)&As[wm * 64 + mt * 16 + l15][kk * 32 + quad * 8];
      for (int nt = 0; nt < 4; nt++) b[nt] = *(half8*)&Bs[wn * 64 + nt * 16 + l15][kk * 32 + quad * 8];
      for (int mt = 0; mt < 4; mt++)
        for (int nt = 0; nt < 4; nt++)
          acc[mt * 4 + nt] = MFMA16(a[mt], b[nt], acc[mt * 4 + nt], 0, 0, 0);
    }
  }
  for (int mt = 0; mt < 4; mt++)
    for (int nt = 0; nt < 4; nt++) {
      int d = bn * 128 + wn * 64 + nt * 16 + l15;
      int tok0 = bm * 128 + wm * 64 + mt * 16 + quad * 4;
      int bb = tok0 >> 11, ntok = tok0 & 2047;
      half4v p;
      for (int r = 0; r < 4; r++) p[r] = f2h(acc[mt * 4 + nt][r]);
      *(half4v*)(Vt + (size_t)(bb * 768 + d) * 2048 + ntok) = p;
    }
}

// ---------------- flash attention v5: 8 waves, 16-key/96-d slices per wave ----------------
__global__ __launch_bounds__(512, 4) void attn_kernel(const _Float16* __restrict__ H,
    const float* __restrict__ X, const _Float16* __restrict__ Vt, float* __restrict__ out) {
  __shared__ _Float16 Qs[32][776];   // 49,664 B
  __shared__ _Float16 Pl[32][136];   //  8,704 B
  __shared__ float pm[8][32];        //  1,024 B
  __shared__ float psum[8][32];      //  1,024 B
  __shared__ float m_run[32], l_run[32];

  int id = blockIdx.x;
  int b = id & 7;          // batch -> XCD
  int q0 = (id >> 3) * 32;
  int tid = threadIdx.x;
  int lane = tid & 63, w = tid >> 6;          // w in 0..7
  int l15 = lane & 15, quad = lane >> 4;

  if (tid < 32) { m_run[tid] = -1e30f; l_run[tid] = 0.f; }

  floatx4 accO[12];   // 6 d-tiles x 2 q-subtiles (wave owns d [w*96, +96))
  for (int i = 0; i < 12; i++) accO[i] = (floatx4){0.f, 0.f, 0.f, 0.f};

  const float*    Xq    = X + (size_t)(b * 2048 + q0) * 768;
  const _Float16* Hbase = H + (size_t)(b * 2048) * 768;
  const _Float16* Vbase = Vt + (size_t)b * 768 * 2048;

  // stage queries: X fp32 -> Qs fp16 (32 x 768), 3072 half8 chunks / 512 thr
  for (int i = 0; i < 6; i++) {
    int f = i * 512 + tid;
    int row = f / 96, c8 = (f % 96) * 8;
    float4 a = *(const float4*)(Xq + (size_t)row * 768 + c8);
    float4 c = *(const float4*)(Xq + (size_t)row * 768 + c8 + 4);
    *(half8*)&Qs[row][c8] = (half8){f2h(a.x), f2h(a.y), f2h(a.z), f2h(a.w),
                                    f2h(c.x), f2h(c.y), f2h(c.z), f2h(c.w)};
  }
  __syncthreads();

  for (int m0 = 0; m0 < 2048; m0 += 128) {
    // ======== S = Q H^T : 32 q-rows x 128 keys; wave w: keys [w*16,+16) ========
    floatx4 sa0 = (floatx4){0.f,0.f,0.f,0.f}, sa1 = (floatx4){0.f,0.f,0.f,0.f};
    const _Float16* Kr = Hbase + (size_t)(m0 + w * 16 + l15) * 768 + quad * 8;
    half8 kpre[4];
    #pragma unroll
    for (int i = 0; i < 4; i++) kpre[i] = *(const half8*)(Kr + i * 32);
    #pragma unroll
    for (int kb = 0; kb < 24; kb++) {
      half8 kcur = kpre[kb & 3];
      half8 qa0 = *(half8*)&Qs[l15][kb * 32 + quad * 8];
      half8 qa1 = *(half8*)&Qs[16 + l15][kb * 32 + quad * 8];
      int nxt = (kb + 4 < 24) ? (kb + 4) * 32 : 0;
      kpre[kb & 3] = *(const half8*)(Kr + nxt);
      sa0 = MFMA16(qa0, kcur, sa0, 0, 0, 0);
      sa1 = MFMA16(qa1, kcur, sa1, 0, 0, 0);
    }
    // hoist first PV V loads (wave owns d [w*96,+96))
    const _Float16* vb0 = Vbase + (size_t)(w * 96 + l15) * 2048 + m0 + quad * 8;
    half8 vpre0 = *(const half8*)vb0;
    half8 vpre1 = *(const half8*)(vb0 + (size_t)16 * 2048);

    // ======== wave-local row max over this wave's 16 keys ========
    float mv[8];
    #pragma unroll
    for (int i = 0; i < 8; i++) mv[i] = (i < 4) ? sa0[i & 3] : sa1[i & 3];
    #pragma unroll
    for (int mask = 1; mask <= 8; mask <<= 1)
      #pragma unroll
      for (int i = 0; i < 8; i++) mv[i] = fmaxf(mv[i], __shfl_xor(mv[i], mask));
    if (l15 == 0) {
      #pragma unroll
      for (int r = 0; r < 4; r++) { pm[w][quad * 4 + r] = mv[r]; pm[w][16 + quad * 4 + r] = mv[4 + r]; }
    }
    __syncthreads();   // barrier A
    float mnew[8], alpha[8];
    #pragma unroll
    for (int i = 0; i < 8; i++) {
      int row = (i >> 2) * 16 + quad * 4 + (i & 3);
      float mo = m_run[row];
      float mn = mo;
      #pragma unroll
      for (int w2 = 0; w2 < 8; w2++) mn = fmaxf(mn, pm[w2][row]);
      mnew[i] = mn;
      alpha[i] = __expf(mo - mn);
    }
    float pr[8];
    #pragma unroll
    for (int i = 0; i < 8; i++) {
      int ss = i >> 2, r = i & 3;
      int row = ss * 16 + quad * 4 + r;
      float p = __expf(((ss == 0) ? sa0[r] : sa1[r]) - mnew[i]);
      pr[i] = p;
      Pl[row][w * 16 + l15] = f2h(p);
    }
    #pragma unroll
    for (int mask = 1; mask <= 8; mask <<= 1)
      #pragma unroll
      for (int i = 0; i < 8; i++) pr[i] += __shfl_xor(pr[i], mask);
    if (l15 == 0) {
      #pragma unroll
      for (int r = 0; r < 4; r++) { psum[w][quad * 4 + r] = pr[r]; psum[w][16 + quad * 4 + r] = pr[4 + r]; }
    }
    // rescale O while Pl/psum settle
    #pragma unroll
    for (int nt = 0; nt < 6; nt++)
      #pragma unroll
      for (int i = 0; i < 8; i++)
        accO[nt * 2 + (i >> 2)][i & 3] *= alpha[i];
    __syncthreads();   // barrier B
    if (w == 0 && l15 == 0) {
      #pragma unroll
      for (int i = 0; i < 8; i++) {
        int row = (i >> 2) * 16 + quad * 4 + (i & 3);
        float s = 0.f;
        #pragma unroll
        for (int w2 = 0; w2 < 8; w2++) s += psum[w2][row];
        l_run[row] = l_run[row] * alpha[i] + s;
        m_run[row] = mnew[i];
      }
    }
    // ======== O += P V : 128 keys, 6 d-tiles ========
    #pragma unroll
    for (int ks = 0; ks < 4; ks++) {
      half8 pa0 = *(half8*)&Pl[l15][ks * 32 + quad * 8];
      half8 pa1 = *(half8*)&Pl[16 + l15][ks * 32 + quad * 8];
      #pragma unroll
      for (int nt = 0; nt < 6; nt++) {
        int idx = ks * 6 + nt;
        half8 vcur = (idx & 1) ? vpre1 : vpre0;
        int nidx = idx + 2;
        if (nidx < 24) {
          int nks = nidx / 6, nnt = nidx % 6;
          half8 nv = *(const half8*)(vb0 + (size_t)nnt * 16 * 2048 + nks * 32);
          if (idx & 1) vpre1 = nv; else vpre0 = nv;
        }
        accO[nt * 2 + 0] = MFMA16(pa0, vcur, accO[nt * 2 + 0], 0, 0, 0);
        accO[nt * 2 + 1] = MFMA16(pa1, vcur, accO[nt * 2 + 1], 0, 0, 0);
      }
    }
  }
  __syncthreads();
  float il[8];
  #pragma unroll
  for (int i = 0; i < 8; i++) {
    int row = (i >> 2) * 16 + quad * 4 + (i & 3);
    il[i] = 1.f / l_run[row];
  }
  #pragma unroll
  for (int nt = 0; nt < 6; nt++)
    #pragma unroll
    for (int ss = 0; ss < 2; ss++) {
      int d = w * 96 + nt * 16 + l15;
      #pragma unroll
      for (int r = 0; r < 4; r++) {
        int row = q0 + ss * 16 + quad * 4 + r;
        out[(size_t)(b * 2048 + row) * 768 + d] = accO[nt * 2 + ss][r] * il[ss * 4 + r];
      }
    }
}

extern "C" void kernel_launch(void* const* d_in, const int* in_sizes, int n_in,
                              void* d_out, int out_size, void* d_ws, size_t ws_size,
                              hipStream_t stream) {
  (void)in_sizes; (void)n_in; (void)out_size; (void)ws_size;
  const float* X  = (const float*)d_in[0];
  const float* Wq = (const float*)d_in[1];
  const float* Wk = (const float*)d_in[2];
  const float* Wv = (const float*)d_in[3];
  float* out = (float*)d_out;

  char* ws = (char*)d_ws;
  _Float16* H  = (_Float16*)ws;                        // 25,165,824 B
  _Float16* Vt = (_Float16*)(ws + 25165824);           // 25,165,824 B

  float*    M   = (float*)d_out;                       // scratch in out (fp32 768x768)
  _Float16* WvT = (_Float16*)((char*)d_out + 2359296); // scratch in out

  mm_small_kernel<<<dim3(6, 6), 256, 0, stream>>>(Wq, Wk, M);
  pack_wv_kernel<<<dim3(24, 24), dim3(32, 8), 0, stream>>>(Wv, WvT);
  proj_h_kernel<<<dim3(6, 128), 256, 0, stream>>>(X, M, H);
  proj_v_kernel<<<dim3(6, 128), 256, 0, stream>>>(X, WvT, Vt);
  attn_kernel<<<512, 512, 0, stream>>>(H, X, Vt, out);
}

// Round 6
// 477.727 us; speedup vs baseline: 1.6795x; 1.2715x over previous
//
#include <hip/hip_runtime.h>

// B=8, N=2048, D=F=768. out = softmax((X Wq)(X Wk)^T) (X Wv), fp32 I/O.
// Identity: S[q][k] = sum_d X[q][d] * H[k][d],  H = X * M^T,  M = Wq Wk^T.
// ws: H = fp16(X M^T) [16384][768] | Vt = fp16(X Wv)^T [8][768][2048]  (50,331,648 B)
// d_out scratch (consumed before attn writes out): M fp32 row-major, WvT fp16.
// attn v6: Qtile=64, 256 blocks (1/CU), 512 thr / 8 waves; wave w: 16-key slice (S),
//   96-d slice (PV). Traffic = 1.61 GB (vs 3.22 in v5); batch->XCD sync walk keeps
//   the 393KB K/V tile L2-resident.

typedef __attribute__((ext_vector_type(8))) _Float16 half8;
typedef __attribute__((ext_vector_type(4))) _Float16 half4v;
typedef __attribute__((ext_vector_type(4))) float floatx4;

__device__ __forceinline__ _Float16 f2h(float f) { return (_Float16)f; }
#define MFMA16 __builtin_amdgcn_mfma_f32_16x16x32_f16

// ---------------- M[d][e] = (Wq Wk^T), fp32 row-major ----------------
__global__ __launch_bounds__(256) void mm_small_kernel(const float* __restrict__ Wq,
    const float* __restrict__ Wk, float* __restrict__ M) {
  __shared__ _Float16 As[128][72];
  __shared__ _Float16 Bs[128][72];
  int bn = blockIdx.x, bm = blockIdx.y;
  int tid = threadIdx.x, lane = tid & 63, wave = tid >> 6;
  int wm = wave >> 1, wn = wave & 1;
  int l15 = lane & 15, quad = lane >> 4;
  floatx4 acc[16];
  for (int i = 0; i < 16; i++) acc[i] = (floatx4){0.f, 0.f, 0.f, 0.f};
  for (int k0 = 0; k0 < 768; k0 += 64) {
    __syncthreads();
    for (int i = 0; i < 8; i++) {
      int f = i * 256 + tid;
      int row = f >> 4, c4 = (f & 15) << 2;
      float4 va = *(const float4*)(Wq + (size_t)(bm * 128 + row) * 768 + k0 + c4);
      *(half4v*)&As[row][c4] = (half4v){f2h(va.x), f2h(va.y), f2h(va.z), f2h(va.w)};
      float4 vb = *(const float4*)(Wk + (size_t)(bn * 128 + row) * 768 + k0 + c4);
      *(half4v*)&Bs[row][c4] = (half4v){f2h(vb.x), f2h(vb.y), f2h(vb.z), f2h(vb.w)};
    }
    __syncthreads();
    for (int kk = 0; kk < 2; kk++) {
      half8 a[4], b[4];
      for (int mt = 0; mt < 4; mt++) a[mt] = *(half8*)&As[wm * 64 + mt * 16 + l15][kk * 32 + quad * 8];
      for (int nt = 0; nt < 4; nt++) b[nt] = *(half8*)&Bs[wn * 64 + nt * 16 + l15][kk * 32 + quad * 8];
      for (int mt = 0; mt < 4; mt++)
        for (int nt = 0; nt < 4; nt++)
          acc[mt * 4 + nt] = MFMA16(a[mt], b[nt], acc[mt * 4 + nt], 0, 0, 0);
    }
  }
  for (int mt = 0; mt < 4; mt++)
    for (int nt = 0; nt < 4; nt++) {
      int e = bn * 128 + wn * 64 + nt * 16 + l15;
      for (int r = 0; r < 4; r++) {
        int d = bm * 128 + wm * 64 + mt * 16 + quad * 4 + r;
        M[(size_t)d * 768 + e] = acc[mt * 4 + nt][r];
      }
    }
}

// ---------------- WvT[e][d] = Wv[d][e], fp16 ----------------
__global__ void pack_wv_kernel(const float* __restrict__ Wv, _Float16* __restrict__ WvT) {
  __shared__ float tile[32][33];
  int k0 = blockIdx.x * 32;
  int n0 = blockIdx.y * 32;
  int tx = threadIdx.x, ty = threadIdx.y;
  for (int yy = ty; yy < 32; yy += 8)
    tile[yy][tx] = Wv[(size_t)(k0 + yy) * 768 + n0 + tx];
  __syncthreads();
  for (int yy = ty; yy < 32; yy += 8)
    WvT[(size_t)(n0 + yy) * 768 + k0 + tx] = f2h(tile[tx][yy]);
}

// ---------------- H = fp16(X * M^T) ----------------
__global__ __launch_bounds__(256) void proj_h_kernel(const float* __restrict__ X,
    const float* __restrict__ M, _Float16* __restrict__ H) {
  __shared__ _Float16 As[128][72];
  __shared__ _Float16 Bs[128][72];
  int bn = blockIdx.x, bm = blockIdx.y;
  int tid = threadIdx.x, lane = tid & 63, wave = tid >> 6;
  int wm = wave >> 1, wn = wave & 1;
  int l15 = lane & 15, quad = lane >> 4;
  floatx4 acc[16];
  for (int i = 0; i < 16; i++) acc[i] = (floatx4){0.f, 0.f, 0.f, 0.f};
  for (int k0 = 0; k0 < 768; k0 += 64) {
    __syncthreads();
    for (int i = 0; i < 8; i++) {
      int f = i * 256 + tid;
      int row = f >> 4, c4 = (f & 15) << 2;
      float4 va = *(const float4*)(X + (size_t)(bm * 128 + row) * 768 + k0 + c4);
      *(half4v*)&As[row][c4] = (half4v){f2h(va.x), f2h(va.y), f2h(va.z), f2h(va.w)};
      float4 vb = *(const float4*)(M + (size_t)(bn * 128 + row) * 768 + k0 + c4);
      *(half4v*)&Bs[row][c4] = (half4v){f2h(vb.x), f2h(vb.y), f2h(vb.z), f2h(vb.w)};
    }
    __syncthreads();
    for (int kk = 0; kk < 2; kk++) {
      half8 a[4], b[4];
      for (int mt = 0; mt < 4; mt++) a[mt] = *(half8*)&As[wm * 64 + mt * 16 + l15][kk * 32 + quad * 8];
      for (int nt = 0; nt < 4; nt++) b[nt] = *(half8*)&Bs[wn * 64 + nt * 16 + l15][kk * 32 + quad * 8];
      for (int mt = 0; mt < 4; mt++)
        for (int nt = 0; nt < 4; nt++)
          acc[mt * 4 + nt] = MFMA16(a[mt], b[nt], acc[mt * 4 + nt], 0, 0, 0);
    }
  }
  for (int mt = 0; mt < 4; mt++)
    for (int nt = 0; nt < 4; nt++) {
      int col = bn * 128 + wn * 64 + nt * 16 + l15;
      for (int r = 0; r < 4; r++) {
        int row = bm * 128 + wm * 64 + mt * 16 + quad * 4 + r;
        H[(size_t)row * 768 + col] = f2h(acc[mt * 4 + nt][r]);
      }
    }
}

// ---------------- Vt[b][d][n] = fp16(X * Wv)^T ----------------
__global__ __launch_bounds__(256) void proj_v_kernel(const float* __restrict__ X,
    const _Float16* __restrict__ WvT, _Float16* __restrict__ Vt) {
  __shared__ _Float16 As[128][72];
  __shared__ _Float16 Bs[128][72];
  int bn = blockIdx.x, bm = blockIdx.y;
  int tid = threadIdx.x, lane = tid & 63, wave = tid >> 6;
  int wm = wave >> 1, wn = wave & 1;
  int l15 = lane & 15, quad = lane >> 4;
  floatx4 acc[16];
  for (int i = 0; i < 16; i++) acc[i] = (floatx4){0.f, 0.f, 0.f, 0.f};
  for (int k0 = 0; k0 < 768; k0 += 64) {
    __syncthreads();
    for (int i = 0; i < 8; i++) {
      int f = i * 256 + tid;
      int row = f >> 4, c4 = (f & 15) << 2;
      float4 va = *(const float4*)(X + (size_t)(bm * 128 + row) * 768 + k0 + c4);
      *(half4v*)&As[row][c4] = (half4v){f2h(va.x), f2h(va.y), f2h(va.z), f2h(va.w)};
    }
    for (int i = 0; i < 4; i++) {
      int f = i * 256 + tid;
      int row = f >> 3, c8 = (f & 7) << 3;
      *(half8*)&Bs[row][c8] = *(const half8*)(WvT + (size_t)(bn * 128 + row) * 768 + k0 + c8);
    }
    __syncthreads();
    for (int kk = 0; kk < 2; kk++) {
      half8 a[4], b[4];
      for (int mt = 0; mt < 4; mt++) a[mt] = *(half8*)&As[wm * 64 + mt * 16 + l15][kk * 32 + quad * 8];
      for (int nt = 0; nt < 4; nt++) b[nt] = *(half8*)&Bs[wn * 64 + nt * 16 + l15][kk * 32 + quad * 8];
      for (int mt = 0; mt < 4; mt++)
        for (int nt = 0; nt < 4; nt++)
          acc[mt * 4 + nt] = MFMA16(a[mt], b[nt], acc[mt * 4 + nt], 0, 0, 0);
    }
  }
  for (int mt = 0; mt < 4; mt++)
    for (int nt = 0; nt < 4; nt++) {
      int d = bn * 128 + wn * 64 + nt * 16 + l15;
      int tok0 = bm * 128 + wm * 64 + mt * 16 + quad * 4;
      int bb = tok0 >> 11, ntok = tok0 & 2047;
      half4v p;
      for (int r = 0; r < 4; r++) p[r] = f2h(acc[mt * 4 + nt][r]);
      *(half4v*)(Vt + (size_t)(bb * 768 + d) * 2048 + ntok) = p;
    }
}

// ---------------- flash attention v6: Qtile=64, 8 waves, 16-key/96-d per wave ----------------
__global__ __launch_bounds__(512, 2) void attn_kernel(const _Float16* __restrict__ H,
    const float* __restrict__ X, const _Float16* __restrict__ Vt, float* __restrict__ out) {
  __shared__ _Float16 Qs[64][776];   // 99,328 B
  __shared__ _Float16 Pl[64][136];   // 17,408 B
  __shared__ float pm[8][64];        //  2,048 B
  __shared__ float psum[8][64];      //  2,048 B
  __shared__ float m_run[64], l_run[64], gmax[64], galpha[64];  // 1,024 B

  int id = blockIdx.x;
  int b = id & 7;            // batch -> XCD
  int q0 = (id >> 3) * 64;   // 32 q-tiles per batch
  int tid = threadIdx.x;
  int lane = tid & 63, w = tid >> 6;   // w in 0..7
  int l15 = lane & 15, quad = lane >> 4;

  if (tid < 64) { m_run[tid] = -1e30f; l_run[tid] = 0.f; }

  floatx4 accO[24];   // [nt][ss]: 6 d-tiles x 4 q-subtiles; wave owns d [w*96,+96)
  for (int i = 0; i < 24; i++) accO[i] = (floatx4){0.f, 0.f, 0.f, 0.f};

  const float*    Xq    = X + (size_t)(b * 2048 + q0) * 768;
  const _Float16* Hbase = H + (size_t)(b * 2048) * 768;
  const _Float16* Vbase = Vt + (size_t)b * 768 * 2048;

  // stage queries: X fp32 -> Qs fp16 (64 x 768), 6144 half8 chunks / 512 thr
  for (int i = 0; i < 12; i++) {
    int f = i * 512 + tid;
    int row = f / 96, c8 = (f % 96) * 8;
    float4 a = *(const float4*)(Xq + (size_t)row * 768 + c8);
    float4 c = *(const float4*)(Xq + (size_t)row * 768 + c8 + 4);
    *(half8*)&Qs[row][c8] = (half8){f2h(a.x), f2h(a.y), f2h(a.z), f2h(a.w),
                                    f2h(c.x), f2h(c.y), f2h(c.z), f2h(c.w)};
  }
  __syncthreads();

  for (int m0 = 0; m0 < 2048; m0 += 128) {
    // ======== S = Q H^T : 64 q-rows x 128 keys; wave w: keys [w*16,+16) ========
    floatx4 sa[4];
    #pragma unroll
    for (int ss = 0; ss < 4; ss++) sa[ss] = (floatx4){0.f, 0.f, 0.f, 0.f};
    const _Float16* Kr = Hbase + (size_t)(m0 + w * 16 + l15) * 768 + quad * 8;
    half8 kpre[4];
    #pragma unroll
    for (int i = 0; i < 4; i++) kpre[i] = *(const half8*)(Kr + i * 32);
    #pragma unroll
    for (int kb = 0; kb < 24; kb++) {
      half8 kcur = kpre[kb & 3];
      int nxt = (kb + 4 < 24) ? (kb + 4) * 32 : 0;
      kpre[kb & 3] = *(const half8*)(Kr + nxt);
      #pragma unroll
      for (int ss = 0; ss < 4; ss++) {
        half8 qa = *(half8*)&Qs[ss * 16 + l15][kb * 32 + quad * 8];
        sa[ss] = MFMA16(qa, kcur, sa[ss], 0, 0, 0);
      }
    }
    // hoist first PV V loads (wave owns d [w*96,+96))
    const _Float16* vb0 = Vbase + (size_t)(w * 96 + l15) * 2048 + m0 + quad * 8;
    half8 vpre[4];
    #pragma unroll
    for (int i = 0; i < 4; i++) {
      int nks = i / 6, nnt = i % 6;
      vpre[i] = *(const half8*)(vb0 + (size_t)nnt * 16 * 2048 + nks * 32);
    }

    // ======== wave-local row max over this wave's 16 keys ========
    float mv[16];
    #pragma unroll
    for (int i = 0; i < 16; i++) mv[i] = sa[i >> 2][i & 3];
    #pragma unroll
    for (int mask = 1; mask <= 8; mask <<= 1)
      #pragma unroll
      for (int i = 0; i < 16; i++) mv[i] = fmaxf(mv[i], __shfl_xor(mv[i], mask));
    if (l15 == 0) {
      #pragma unroll
      for (int i = 0; i < 16; i++) pm[w][(i >> 2) * 16 + quad * 4 + (i & 3)] = mv[i];
    }
    __syncthreads();   // barrier A: pm visible
    if (tid < 64) {    // combine wave maxes once; update m_run (only these threads touch it)
      float mo = m_run[tid];
      float mn = mo;
      #pragma unroll
      for (int w2 = 0; w2 < 8; w2++) mn = fmaxf(mn, pm[w2][tid]);
      gmax[tid] = mn;
      galpha[tid] = __expf(mo - mn);   // first tile: exp(-1e30)=0
      m_run[tid] = mn;
    }
    __syncthreads();   // barrier A2: gmax/galpha visible
    // ======== exp in regs -> Pl (A-layout), row partial sums ========
    float pr[16], al[16];
    #pragma unroll
    for (int i = 0; i < 16; i++) {
      int ss = i >> 2, r = i & 3;
      int row = ss * 16 + quad * 4 + r;
      float mn = gmax[row];
      al[i] = galpha[row];
      float p = __expf(sa[ss][r] - mn);
      pr[i] = p;
      Pl[row][w * 16 + l15] = f2h(p);
    }
    #pragma unroll
    for (int mask = 1; mask <= 8; mask <<= 1)
      #pragma unroll
      for (int i = 0; i < 16; i++) pr[i] += __shfl_xor(pr[i], mask);
    if (l15 == 0) {
      #pragma unroll
      for (int i = 0; i < 16; i++) psum[w][(i >> 2) * 16 + quad * 4 + (i & 3)] = pr[i];
    }
    // rescale O while Pl/psum settle
    #pragma unroll
    for (int nt = 0; nt < 6; nt++)
      #pragma unroll
      for (int i = 0; i < 16; i++)
        accO[nt * 4 + (i >> 2)][i & 3] *= al[i];
    __syncthreads();   // barrier B: Pl + psum visible
    if (tid < 64) {    // fold l_run (parallel over 64 rows)
      float s = 0.f;
      #pragma unroll
      for (int w2 = 0; w2 < 8; w2++) s += psum[w2][tid];
      l_run[tid] = l_run[tid] * galpha[tid] + s;
    }
    // ======== O += P V : 128 keys, 6 d-tiles x 4 q-subtiles ========
    #pragma unroll
    for (int ks = 0; ks < 4; ks++) {
      half8 pa[4];
      #pragma unroll
      for (int ss = 0; ss < 4; ss++) pa[ss] = *(half8*)&Pl[ss * 16 + l15][ks * 32 + quad * 8];
      #pragma unroll
      for (int nt = 0; nt < 6; nt++) {
        int idx = ks * 6 + nt;
        half8 vcur = vpre[idx & 3];
        int nidx = idx + 4;
        int nks = (nidx < 24) ? nidx / 6 : 0;
        int nnt = (nidx < 24) ? nidx % 6 : 0;
        vpre[idx & 3] = *(const half8*)(vb0 + (size_t)nnt * 16 * 2048 + nks * 32);
        #pragma unroll
        for (int ss = 0; ss < 4; ss++)
          accO[nt * 4 + ss] = MFMA16(pa[ss], vcur, accO[nt * 4 + ss], 0, 0, 0);
      }
    }
  }
  __syncthreads();   // l_run final visible
  float il[16];
  #pragma unroll
  for (int i = 0; i < 16; i++) {
    int row = (i >> 2) * 16 + quad * 4 + (i & 3);
    il[i] = 1.f / l_run[row];
  }
  #pragma unroll
  for (int nt = 0; nt < 6; nt++)
    #pragma unroll
    for (int ss = 0; ss < 4; ss++) {
      int d = w * 96 + nt * 16 + l15;
      #pragma unroll
      for (int r = 0; r < 4; r++) {
        int row = q0 + ss * 16 + quad * 4 + r;
        out[(size_t)(b * 2048 + row) * 768 + d] = accO[nt * 4 + ss][r] * il[ss * 4 + r];
      }
    }
}

extern "C" void kernel_launch(void* const* d_in, const int* in_sizes, int n_in,
                              void* d_out, int out_size, void* d_ws, size_t ws_size,
                              hipStream_t stream) {
  (void)in_sizes; (void)n_in; (void)out_size; (void)ws_size;
  const float* X  = (const float*)d_in[0];
  const float* Wq = (const float*)d_in[1];
  const float* Wk = (const float*)d_in[2];
  const float* Wv = (const float*)d_in[3];
  float* out = (float*)d_out;

  char* ws = (char*)d_ws;
  _Float16* H  = (_Float16*)ws;                        // 25,165,824 B
  _Float16* Vt = (_Float16*)(ws + 25165824);           // 25,165,824 B

  float*    M   = (float*)d_out;                       // scratch in out (fp32 768x768)
  _Float16* WvT = (_Float16*)((char*)d_out + 2359296); // scratch in out

  mm_small_kernel<<<dim3(6, 6), 256, 0, stream>>>(Wq, Wk, M);
  pack_wv_kernel<<<dim3(24, 24), dim3(32, 8), 0, stream>>>(Wv, WvT);
  proj_h_kernel<<<dim3(6, 128), 256, 0, stream>>>(X, M, H);
  proj_v_kernel<<<dim3(6, 128), 256, 0, stream>>>(X, WvT, Vt);
  attn_kernel<<<256, 512, 0, stream>>>(H, X, Vt, out);
}